// Round 3
// baseline (647.888 us; speedup 1.0000x reference)
//
#include <hip/hip_runtime.h>
#include <hip/hip_bf16.h>

// BasicBlock sparse conv v3: output-centric gather conv, bf16 MFMA.
// Key change vs v2: vmem issue order made prefetch-monotone (idx(k+4), B(k+1),
// A(k+2), then MFMA(k)) so in-order vmcnt retirement never drains younger
// prefetches. h stored as bf16 (BN stats taken from fp32 regs before rounding).

#define N_VOX 200000
#define NP 200064            // padded rows: 1563 blocks * 128 rows
#define P_PAIR 65536
#define EPS_BN 1e-5f

typedef __attribute__((ext_vector_type(8))) short bf16x8;   // 8 bf16 = 4 VGPRs
typedef __attribute__((ext_vector_type(4))) float f32x4;

// ---------------- prep kernels ----------------

__global__ void fill_kernel(int* __restrict__ nbrT, float* __restrict__ sums) {
    int p = blockIdx.y;                                   // plane 0..26
    long i = ((long)blockIdx.x * 256 + threadIdx.x) * 4;  // element in plane
    if (i < NP) {
        int4 v;
        if (p == 13) {   // identity plane (center tap); pad rows -> zero row
            v.x = (i + 0 < N_VOX) ? (int)i + 0 : N_VOX;
            v.y = (i + 1 < N_VOX) ? (int)i + 1 : N_VOX;
            v.z = (i + 2 < N_VOX) ? (int)i + 2 : N_VOX;
            v.w = (i + 3 < N_VOX) ? (int)i + 3 : N_VOX;
        } else {
            v.x = v.y = v.z = v.w = N_VOX;                // sentinel -> zero row
        }
        *(int4*)(nbrT + (long)p * NP + i) = v;
    }
    if (p == 0 && blockIdx.x == 0 && threadIdx.x < 64) {  // zero sums[256]
        float4 z = {0.f, 0.f, 0.f, 0.f};
        ((float4*)sums)[threadIdx.x] = z;
    }
}

__global__ void scatter_kernel(const int* __restrict__ out_maps,
                               const int* __restrict__ in_maps,
                               int* __restrict__ nbrT) {
    int idx = blockIdx.x * 256 + threadIdx.x;       // < 26*65536
    int o = out_maps[idx];
    if (o < N_VOX) {
        int k = idx >> 16;                          // offset index 0..25
        int p = k + (k >= 13);                      // weight plane (skip center)
        nbrT[(long)p * NP + o] = in_maps[idx];
    }
}

__global__ void cast_x_kernel(const float* __restrict__ x,
                              __hip_bfloat16* __restrict__ xb) {
    long i = ((long)blockIdx.x * 256 + threadIdx.x) * 4;
    if (i >= (long)(N_VOX + 1) * 64) return;
    __hip_bfloat16 t[4];
    if (i < (long)N_VOX * 64) {
        float4 v = *(const float4*)(x + i);
        t[0] = __float2bfloat16(v.x); t[1] = __float2bfloat16(v.y);
        t[2] = __float2bfloat16(v.z); t[3] = __float2bfloat16(v.w);
    } else {
        t[0] = t[1] = t[2] = t[3] = __float2bfloat16(0.0f);  // zero row N
    }
    *(ushort4*)(xb + i) = *(ushort4*)t;
}

// WT[k][d][c] = W[k][c][d]  (bf16; B-fragments are contiguous 16B per lane)
__global__ void cast_w_kernel(const float* __restrict__ W1, const float* __restrict__ W2,
                              __hip_bfloat16* __restrict__ W1T, __hip_bfloat16* __restrict__ W2T) {
    int idx = blockIdx.x * 256 + threadIdx.x;
    if (idx >= 27 * 4096) return;
    int k = idx >> 12, rem = idx & 4095;
    int d = rem >> 6, c = rem & 63;
    int src = k * 4096 + c * 64 + d;
    W1T[idx] = __float2bfloat16(W1[src]);
    W2T[idx] = __float2bfloat16(W2[src]);
}

// ---------------- conv kernel ----------------
// block = 4 waves; wave computes 32 rows (2 MFMA row-tiles) x 64 cols.
// Per iter k vmem order: idx(k+4) -> B(k+1) -> A(k+2) -> MFMA(k).
// In-order vmcnt: MFMA(k)'s operands are older than all prefetches -> no drain.

__global__ __launch_bounds__(256, 3) void conv_kernel(
    const __hip_bfloat16* __restrict__ xb,   // [(N+1)*64]
    const __hip_bfloat16* __restrict__ WT,   // [27*64*64]
    const int* __restrict__ nbrT,            // [27*NP]
    __hip_bfloat16* __restrict__ h,          // [N*64] bf16
    float* __restrict__ sums)                // [128]: sum[64], sumsq[64]
{
    const int tid  = threadIdx.x;
    const int lane = tid & 63;
    const int wave = tid >> 6;
    const int m    = lane & 15;
    const int quad = lane >> 4;
    const int rbase = (blockIdx.x * 4 + wave) * 32;   // 32 rows per wave
    const int o0 = rbase + m;                          // tile0 row for this lane

    const int* __restrict__ ip = nbrT + o0;            // tile1 at +16

    f32x4 acc[8];   // [tile*4 + ctile]
#pragma unroll
    for (int i = 0; i < 8; ++i) acc[i] = (f32x4){0.f, 0.f, 0.f, 0.f};

    const __hip_bfloat16* __restrict__ wfrag = WT + m * 64 + quad * 8;

    int id0[4], id1[4];        // idx ring, depth 4
    bf16x8 A[3][2][2];         // A ring, depth 3: [stage][tile][half]
    bf16x8 B[2][8];            // B ring, depth 2: [stage][ct*2+half]

#pragma unroll
    for (int s = 0; s < 4; ++s) {
        id0[s] = ip[(long)s * NP];
        id1[s] = ip[(long)s * NP + 16];
    }
    {   // B(0)
#pragma unroll
        for (int ct = 0; ct < 4; ++ct) {
            B[0][ct * 2]     = *(const bf16x8*)(wfrag + ct * 1024);
            B[0][ct * 2 + 1] = *(const bf16x8*)(wfrag + ct * 1024 + 32);
        }
    }
    {   // A(0), A(1)
#pragma unroll
        for (int s = 0; s < 2; ++s) {
            const __hip_bfloat16* r0 = xb + (long)id0[s] * 64 + quad * 8;
            A[s][0][0] = *(const bf16x8*)r0;  A[s][0][1] = *(const bf16x8*)(r0 + 32);
            const __hip_bfloat16* r1 = xb + (long)id1[s] * 64 + quad * 8;
            A[s][1][0] = *(const bf16x8*)r1;  A[s][1][1] = *(const bf16x8*)(r1 + 32);
        }
    }

#pragma unroll
    for (int k = 0; k < 27; ++k) {
        // 1) idx prefetch, plane k+4 (oldest ring slot k%4 is dead: consumed at iter k-2)
        if (k + 4 < 27) {
            id0[(k + 4) & 3] = ip[(long)(k + 4) * NP];
            id1[(k + 4) & 3] = ip[(long)(k + 4) * NP + 16];
        }
        // 2) B prefetch, plane k+1
        if (k + 1 < 27) {
            const __hip_bfloat16* wk = wfrag + (k + 1) * 4096;
#pragma unroll
            for (int ct = 0; ct < 4; ++ct) {
                B[(k + 1) & 1][ct * 2]     = *(const bf16x8*)(wk + ct * 1024);
                B[(k + 1) & 1][ct * 2 + 1] = *(const bf16x8*)(wk + ct * 1024 + 32);
            }
        }
        // 3) A prefetch, plane k+2
        if (k + 2 < 27) {
            const int s = (k + 2) % 3;
            const __hip_bfloat16* r0 = xb + (long)id0[(k + 2) & 3] * 64 + quad * 8;
            A[s][0][0] = *(const bf16x8*)r0;  A[s][0][1] = *(const bf16x8*)(r0 + 32);
            const __hip_bfloat16* r1 = xb + (long)id1[(k + 2) & 3] * 64 + quad * 8;
            A[s][1][0] = *(const bf16x8*)r1;  A[s][1][1] = *(const bf16x8*)(r1 + 32);
        }
        // 4) MFMA for plane k
        const int cs = k % 3, bs = k & 1;
#pragma unroll
        for (int ct = 0; ct < 4; ++ct) {
            acc[ct]     = __builtin_amdgcn_mfma_f32_16x16x32_bf16(A[cs][0][0], B[bs][ct * 2],     acc[ct],     0, 0, 0);
            acc[ct]     = __builtin_amdgcn_mfma_f32_16x16x32_bf16(A[cs][0][1], B[bs][ct * 2 + 1], acc[ct],     0, 0, 0);
            acc[4 + ct] = __builtin_amdgcn_mfma_f32_16x16x32_bf16(A[cs][1][0], B[bs][ct * 2],     acc[4 + ct], 0, 0, 0);
            acc[4 + ct] = __builtin_amdgcn_mfma_f32_16x16x32_bf16(A[cs][1][1], B[bs][ct * 2 + 1], acc[4 + ct], 0, 0, 0);
        }
    }

    const bool valid = rbase < N_VOX;   // whole wave-tile valid or not

    // store h (bf16; BN stats below use the fp32 registers)
    if (valid) {
#pragma unroll
        for (int t = 0; t < 2; ++t) {
            __hip_bfloat16* hp = h + (long)(rbase + t * 16 + quad * 4) * 64 + m;
#pragma unroll
            for (int r = 0; r < 4; ++r) {
#pragma unroll
                for (int ct = 0; ct < 4; ++ct)
                    hp[r * 64 + ct * 16] = __float2bfloat16(acc[t * 4 + ct][r]);
            }
        }
    }

    // fused BN stats: per-channel sum / sumsq over this wave's 32 rows
    __shared__ float lsum[16][64];
    __shared__ float lsq[16][64];
#pragma unroll
    for (int ct = 0; ct < 4; ++ct) {
        float s = 0.f, q = 0.f;
        if (valid) {
#pragma unroll
            for (int t = 0; t < 2; ++t)
#pragma unroll
                for (int r = 0; r < 4; ++r) {
                    float v = acc[t * 4 + ct][r];
                    s += v; q += v * v;
                }
        }
        lsum[wave * 4 + quad][ct * 16 + m] = s;
        lsq [wave * 4 + quad][ct * 16 + m] = q;
    }
    __syncthreads();
    if (tid < 64) {
        float S = 0.f, Q = 0.f;
#pragma unroll
        for (int j = 0; j < 16; ++j) { S += lsum[j][tid]; Q += lsq[j][tid]; }
        atomicAdd(&sums[tid], S);
        atomicAdd(&sums[64 + tid], Q);
    }
}

// ---------------- BN1 + relu + cast to bf16 (conv2 input) ----------------

__global__ void bnrelu_kernel(const __hip_bfloat16* __restrict__ h, const float* __restrict__ sums,
                              const float* __restrict__ gamma, const float* __restrict__ beta,
                              __hip_bfloat16* __restrict__ hb) {
    long i = ((long)blockIdx.x * 256 + threadIdx.x) * 4;
    if (i >= (long)(N_VOX + 1) * 64) return;
    __hip_bfloat16 t[4];
    if (i < (long)N_VOX * 64) {
        int c0 = (int)(i & 63);
        ushort4 raw = *(const ushort4*)(h + i);
        __hip_bfloat16 hv[4];
        *(ushort4*)hv = raw;
#pragma unroll
        for (int j = 0; j < 4; ++j) {
            int c = c0 + j;
            float mu  = sums[c] * (1.0f / N_VOX);
            float var = sums[64 + c] * (1.0f / N_VOX) - mu * mu;
            float rs  = rsqrtf(var + EPS_BN);
            float val = gamma[c] * (__bfloat162float(hv[j]) - mu) * rs + beta[c];
            t[j] = __float2bfloat16(fmaxf(val, 0.0f));
        }
    } else {
        t[0] = t[1] = t[2] = t[3] = __float2bfloat16(0.0f);   // zero row N
    }
    *(ushort4*)(hb + i) = *(ushort4*)t;
}

// ---------------- BN2 + residual + relu -> d_out ----------------

__global__ void final_kernel(const __hip_bfloat16* __restrict__ h, const float* __restrict__ x,
                             const float* __restrict__ sums, const float* __restrict__ gamma,
                             const float* __restrict__ beta, float* __restrict__ out) {
    long i = ((long)blockIdx.x * 256 + threadIdx.x) * 4;
    if (i >= (long)N_VOX * 64) return;
    int c0 = (int)(i & 63);
    ushort4 raw = *(const ushort4*)(h + i);
    __hip_bfloat16 hv[4];
    *(ushort4*)hv = raw;
    float4 xr = *(const float4*)(x + i);
    float xx[4] = {xr.x, xr.y, xr.z, xr.w};
    float oo[4];
#pragma unroll
    for (int j = 0; j < 4; ++j) {
        int c = c0 + j;
        float mu  = sums[c] * (1.0f / N_VOX);
        float var = sums[64 + c] * (1.0f / N_VOX) - mu * mu;
        float rs  = rsqrtf(var + EPS_BN);
        float val = gamma[c] * (__bfloat162float(hv[j]) - mu) * rs + beta[c] + xx[j];
        oo[j] = fmaxf(val, 0.0f);
    }
    float4 ov = {oo[0], oo[1], oo[2], oo[3]};
    *(float4*)(out + i) = ov;
}

// ---------------- launcher ----------------

extern "C" void kernel_launch(void* const* d_in, const int* in_sizes, int n_in,
                              void* d_out, int out_size, void* d_ws, size_t ws_size,
                              hipStream_t stream) {
    const float* x      = (const float*)d_in[0];
    const float* W1     = (const float*)d_in[1];
    const float* gamma1 = (const float*)d_in[2];
    const float* beta1  = (const float*)d_in[3];
    const float* W2     = (const float*)d_in[4];
    const float* gamma2 = (const float*)d_in[5];
    const float* beta2  = (const float*)d_in[6];
    const int* in_maps  = (const int*)d_in[7];
    const int* out_maps = (const int*)d_in[8];
    float* out = (float*)d_out;

    char* ws = (char*)d_ws;
    size_t off = 0;
    auto alloc = [&](size_t bytes) -> void* {
        void* p = ws + off;
        off = (off + bytes + 255) & ~(size_t)255;
        return p;
    };
    int* nbrT           = (int*)alloc((size_t)27 * NP * 4);                    // 21.6 MB
    __hip_bfloat16* xb  = (__hip_bfloat16*)alloc((size_t)(N_VOX + 1) * 64 * 2); // 25.6 MB (reused as h1b)
    __hip_bfloat16* W1T = (__hip_bfloat16*)alloc((size_t)27 * 4096 * 2);
    __hip_bfloat16* W2T = (__hip_bfloat16*)alloc((size_t)27 * 4096 * 2);
    __hip_bfloat16* h   = (__hip_bfloat16*)alloc((size_t)N_VOX * 64 * 2);      // 25.6 MB
    float* sums         = (float*)alloc(256 * 4);
    __hip_bfloat16* h1b = xb;   // xb dead after conv1; reuse for BN1(relu) output

    const long elem_x = (long)(N_VOX + 1) * 64;

    fill_kernel   <<<dim3((NP / 4 + 255) / 256, 27), 256, 0, stream>>>(nbrT, sums);
    scatter_kernel<<<26 * P_PAIR / 256, 256, 0, stream>>>(out_maps, in_maps, nbrT);
    cast_x_kernel <<<(int)((elem_x / 4 + 255) / 256), 256, 0, stream>>>(x, xb);
    cast_w_kernel <<<(27 * 4096 + 255) / 256, 256, 0, stream>>>(W1, W2, W1T, W2T);

    conv_kernel   <<<NP / 128, 256, 0, stream>>>(xb, W1T, nbrT, h, sums);
    bnrelu_kernel <<<(int)((elem_x / 4 + 255) / 256), 256, 0, stream>>>(h, sums, gamma1, beta1, h1b);

    conv_kernel   <<<NP / 128, 256, 0, stream>>>(h1b, W2T, nbrT, h, sums + 128);
    final_kernel  <<<(int)(((long)N_VOX * 64 / 4 + 255) / 256), 256, 0, stream>>>(h, x, sums + 128, gamma2, beta2, out);
}

// Round 4
// 602.493 us; speedup vs baseline: 1.0753x; 1.0753x over previous
//
#include <hip/hip_runtime.h>
#include <hip/hip_bf16.h>

// BasicBlock sparse conv v4: output-centric gather conv, bf16 MFMA.
// v3 failed because the machine scheduler sank all prefetch loads to their
// uses (VGPR=48 proved it). v4 pins the software pipeline with
// sched_barrier(0) fences: per iter k, {idx(k+8), B(k+1), A(k+3)} | fence |
// {MFMA(k)} | fence. Rings: idx depth 8, A depth 4, B depth 2.

#define N_VOX 200000
#define NP 200064            // padded rows: 1563 blocks * 128 rows
#define P_PAIR 65536
#define EPS_BN 1e-5f

typedef __attribute__((ext_vector_type(8))) short bf16x8;   // 8 bf16 = 4 VGPRs
typedef __attribute__((ext_vector_type(4))) float f32x4;

// ---------------- prep kernels ----------------

__global__ void fill_kernel(int* __restrict__ nbrT, float* __restrict__ sums) {
    int p = blockIdx.y;                                   // plane 0..26
    long i = ((long)blockIdx.x * 256 + threadIdx.x) * 4;  // element in plane
    if (i < NP) {
        int4 v;
        if (p == 13) {   // identity plane (center tap); pad rows -> zero row
            v.x = (i + 0 < N_VOX) ? (int)i + 0 : N_VOX;
            v.y = (i + 1 < N_VOX) ? (int)i + 1 : N_VOX;
            v.z = (i + 2 < N_VOX) ? (int)i + 2 : N_VOX;
            v.w = (i + 3 < N_VOX) ? (int)i + 3 : N_VOX;
        } else {
            v.x = v.y = v.z = v.w = N_VOX;                // sentinel -> zero row
        }
        *(int4*)(nbrT + (long)p * NP + i) = v;
    }
    if (p == 0 && blockIdx.x == 0 && threadIdx.x < 64) {  // zero sums[256]
        float4 z = {0.f, 0.f, 0.f, 0.f};
        ((float4*)sums)[threadIdx.x] = z;
    }
}

__global__ void scatter_kernel(const int* __restrict__ out_maps,
                               const int* __restrict__ in_maps,
                               int* __restrict__ nbrT) {
    int idx = blockIdx.x * 256 + threadIdx.x;       // < 26*65536
    int o = out_maps[idx];
    if (o < N_VOX) {
        int k = idx >> 16;                          // offset index 0..25
        int p = k + (k >= 13);                      // weight plane (skip center)
        nbrT[(long)p * NP + o] = in_maps[idx];
    }
}

__global__ void cast_x_kernel(const float* __restrict__ x,
                              __hip_bfloat16* __restrict__ xb) {
    long i = ((long)blockIdx.x * 256 + threadIdx.x) * 4;
    if (i >= (long)(N_VOX + 1) * 64) return;
    __hip_bfloat16 t[4];
    if (i < (long)N_VOX * 64) {
        float4 v = *(const float4*)(x + i);
        t[0] = __float2bfloat16(v.x); t[1] = __float2bfloat16(v.y);
        t[2] = __float2bfloat16(v.z); t[3] = __float2bfloat16(v.w);
    } else {
        t[0] = t[1] = t[2] = t[3] = __float2bfloat16(0.0f);  // zero row N
    }
    *(ushort4*)(xb + i) = *(ushort4*)t;
}

// WT[k][d][c] = W[k][c][d]  (bf16; B-fragments are contiguous 16B per lane)
__global__ void cast_w_kernel(const float* __restrict__ W1, const float* __restrict__ W2,
                              __hip_bfloat16* __restrict__ W1T, __hip_bfloat16* __restrict__ W2T) {
    int idx = blockIdx.x * 256 + threadIdx.x;
    if (idx >= 27 * 4096) return;
    int k = idx >> 12, rem = idx & 4095;
    int d = rem >> 6, c = rem & 63;
    int src = k * 4096 + c * 64 + d;
    W1T[idx] = __float2bfloat16(W1[src]);
    W2T[idx] = __float2bfloat16(W2[src]);
}

// ---------------- conv kernel ----------------
// block = 4 waves; wave computes 32 rows (2 MFMA row-tiles) x 64 cols.
// Pipeline (pinned by sched_barrier(0)):
//   iter k: [ idx(k+8) ; B(k+1) ; A(k+3) ] || [ MFMA(k) ] ||
// In-order vmcnt: MFMA(k)'s newest operand (B(k)) has 18 younger loads ->
// compiler emits vmcnt(~18); prefetches never drained.

__global__ __launch_bounds__(256, 2) void conv_kernel(
    const __hip_bfloat16* __restrict__ xb,   // [(N+1)*64]
    const __hip_bfloat16* __restrict__ WT,   // [27*64*64]
    const int* __restrict__ nbrT,            // [27*NP]
    __hip_bfloat16* __restrict__ h,          // [N*64] bf16
    float* __restrict__ sums)                // [128]: sum[64], sumsq[64]
{
    const int tid  = threadIdx.x;
    const int lane = tid & 63;
    const int wave = tid >> 6;
    const int m    = lane & 15;
    const int quad = lane >> 4;
    const int rbase = (blockIdx.x * 4 + wave) * 32;   // 32 rows per wave
    const int o0 = rbase + m;                          // tile0 row for this lane

    const int* __restrict__ ip = nbrT + o0;            // tile1 at +16

    f32x4 acc[8];   // [tile*4 + ctile]
#pragma unroll
    for (int i = 0; i < 8; ++i) acc[i] = (f32x4){0.f, 0.f, 0.f, 0.f};

    const __hip_bfloat16* __restrict__ wfrag = WT + m * 64 + quad * 8;

    int id0[8], id1[8];        // idx ring, depth 8
    bf16x8 A[4][2][2];         // A ring, depth 4: [stage][tile][half]
    bf16x8 B[2][8];            // B ring, depth 2: [stage][ct*2+half]

    // ---- prologue ----
#pragma unroll
    for (int s = 0; s < 8; ++s) {
        id0[s] = ip[(long)s * NP];
        id1[s] = ip[(long)s * NP + 16];
    }
    {   // B(0)
#pragma unroll
        for (int ct = 0; ct < 4; ++ct) {
            B[0][ct * 2]     = *(const bf16x8*)(wfrag + ct * 1024);
            B[0][ct * 2 + 1] = *(const bf16x8*)(wfrag + ct * 1024 + 32);
        }
    }
    {   // A(0), A(1), A(2)
#pragma unroll
        for (int s = 0; s < 3; ++s) {
            const __hip_bfloat16* r0 = xb + (long)id0[s] * 64 + quad * 8;
            A[s][0][0] = *(const bf16x8*)r0;  A[s][0][1] = *(const bf16x8*)(r0 + 32);
            const __hip_bfloat16* r1 = xb + (long)id1[s] * 64 + quad * 8;
            A[s][1][0] = *(const bf16x8*)r1;  A[s][1][1] = *(const bf16x8*)(r1 + 32);
        }
    }
    __builtin_amdgcn_sched_barrier(0);

    // ---- pinned main loop ----
#pragma unroll
    for (int k = 0; k < 27; ++k) {
        // 1) idx prefetch, plane k+8 (slot k&7 holds idx(k), dead since iter k-3)
        if (k + 8 < 27) {
            id0[(k + 8) & 7] = ip[(long)(k + 8) * NP];
            id1[(k + 8) & 7] = ip[(long)(k + 8) * NP + 16];
        }
        // 2) B prefetch, plane k+1
        if (k + 1 < 27) {
            const __hip_bfloat16* wk = wfrag + (k + 1) * 4096;
#pragma unroll
            for (int ct = 0; ct < 4; ++ct) {
                B[(k + 1) & 1][ct * 2]     = *(const bf16x8*)(wk + ct * 1024);
                B[(k + 1) & 1][ct * 2 + 1] = *(const bf16x8*)(wk + ct * 1024 + 32);
            }
        }
        // 3) A prefetch, plane k+3 (idx(k+3) loaded at iter k-5: ~5 plane-times old)
        if (k + 3 < 27) {
            const int s = (k + 3) & 3;
            const __hip_bfloat16* r0 = xb + (long)id0[(k + 3) & 7] * 64 + quad * 8;
            A[s][0][0] = *(const bf16x8*)r0;  A[s][0][1] = *(const bf16x8*)(r0 + 32);
            const __hip_bfloat16* r1 = xb + (long)id1[(k + 3) & 7] * 64 + quad * 8;
            A[s][1][0] = *(const bf16x8*)r1;  A[s][1][1] = *(const bf16x8*)(r1 + 32);
        }
        __builtin_amdgcn_sched_barrier(0);
        // 4) MFMA for plane k
        const int cs = k & 3, bs = k & 1;
#pragma unroll
        for (int ct = 0; ct < 4; ++ct) {
            acc[ct]     = __builtin_amdgcn_mfma_f32_16x16x32_bf16(A[cs][0][0], B[bs][ct * 2],     acc[ct],     0, 0, 0);
            acc[ct]     = __builtin_amdgcn_mfma_f32_16x16x32_bf16(A[cs][0][1], B[bs][ct * 2 + 1], acc[ct],     0, 0, 0);
            acc[4 + ct] = __builtin_amdgcn_mfma_f32_16x16x32_bf16(A[cs][1][0], B[bs][ct * 2],     acc[4 + ct], 0, 0, 0);
            acc[4 + ct] = __builtin_amdgcn_mfma_f32_16x16x32_bf16(A[cs][1][1], B[bs][ct * 2 + 1], acc[4 + ct], 0, 0, 0);
        }
        __builtin_amdgcn_sched_barrier(0);
    }

    const bool valid = rbase < N_VOX;   // whole wave-tile valid or not

    // store h (bf16; BN stats below use the fp32 registers)
    if (valid) {
#pragma unroll
        for (int t = 0; t < 2; ++t) {
            __hip_bfloat16* hp = h + (long)(rbase + t * 16 + quad * 4) * 64 + m;
#pragma unroll
            for (int r = 0; r < 4; ++r) {
#pragma unroll
                for (int ct = 0; ct < 4; ++ct)
                    hp[r * 64 + ct * 16] = __float2bfloat16(acc[t * 4 + ct][r]);
            }
        }
    }

    // fused BN stats: per-channel sum / sumsq over this wave's 32 rows
    __shared__ float lsum[16][64];
    __shared__ float lsq[16][64];
#pragma unroll
    for (int ct = 0; ct < 4; ++ct) {
        float s = 0.f, q = 0.f;
        if (valid) {
#pragma unroll
            for (int t = 0; t < 2; ++t)
#pragma unroll
                for (int r = 0; r < 4; ++r) {
                    float v = acc[t * 4 + ct][r];
                    s += v; q += v * v;
                }
        }
        lsum[wave * 4 + quad][ct * 16 + m] = s;
        lsq [wave * 4 + quad][ct * 16 + m] = q;
    }
    __syncthreads();
    if (tid < 64) {
        float S = 0.f, Q = 0.f;
#pragma unroll
        for (int j = 0; j < 16; ++j) { S += lsum[j][tid]; Q += lsq[j][tid]; }
        atomicAdd(&sums[tid], S);
        atomicAdd(&sums[64 + tid], Q);
    }
}

// ---------------- BN1 + relu + cast to bf16 (conv2 input) ----------------

__global__ void bnrelu_kernel(const __hip_bfloat16* __restrict__ h, const float* __restrict__ sums,
                              const float* __restrict__ gamma, const float* __restrict__ beta,
                              __hip_bfloat16* __restrict__ hb) {
    long i = ((long)blockIdx.x * 256 + threadIdx.x) * 4;
    if (i >= (long)(N_VOX + 1) * 64) return;
    __hip_bfloat16 t[4];
    if (i < (long)N_VOX * 64) {
        int c0 = (int)(i & 63);
        ushort4 raw = *(const ushort4*)(h + i);
        __hip_bfloat16 hv[4];
        *(ushort4*)hv = raw;
#pragma unroll
        for (int j = 0; j < 4; ++j) {
            int c = c0 + j;
            float mu  = sums[c] * (1.0f / N_VOX);
            float var = sums[64 + c] * (1.0f / N_VOX) - mu * mu;
            float rs  = rsqrtf(var + EPS_BN);
            float val = gamma[c] * (__bfloat162float(hv[j]) - mu) * rs + beta[c];
            t[j] = __float2bfloat16(fmaxf(val, 0.0f));
        }
    } else {
        t[0] = t[1] = t[2] = t[3] = __float2bfloat16(0.0f);   // zero row N
    }
    *(ushort4*)(hb + i) = *(ushort4*)t;
}

// ---------------- BN2 + residual + relu -> d_out ----------------

__global__ void final_kernel(const __hip_bfloat16* __restrict__ h, const float* __restrict__ x,
                             const float* __restrict__ sums, const float* __restrict__ gamma,
                             const float* __restrict__ beta, float* __restrict__ out) {
    long i = ((long)blockIdx.x * 256 + threadIdx.x) * 4;
    if (i >= (long)N_VOX * 64) return;
    int c0 = (int)(i & 63);
    ushort4 raw = *(const ushort4*)(h + i);
    __hip_bfloat16 hv[4];
    *(ushort4*)hv = raw;
    float4 xr = *(const float4*)(x + i);
    float xx[4] = {xr.x, xr.y, xr.z, xr.w};
    float oo[4];
#pragma unroll
    for (int j = 0; j < 4; ++j) {
        int c = c0 + j;
        float mu  = sums[c] * (1.0f / N_VOX);
        float var = sums[64 + c] * (1.0f / N_VOX) - mu * mu;
        float rs  = rsqrtf(var + EPS_BN);
        float val = gamma[c] * (__bfloat162float(hv[j]) - mu) * rs + beta[c] + xx[j];
        oo[j] = fmaxf(val, 0.0f);
    }
    float4 ov = {oo[0], oo[1], oo[2], oo[3]};
    *(float4*)(out + i) = ov;
}

// ---------------- launcher ----------------

extern "C" void kernel_launch(void* const* d_in, const int* in_sizes, int n_in,
                              void* d_out, int out_size, void* d_ws, size_t ws_size,
                              hipStream_t stream) {
    const float* x      = (const float*)d_in[0];
    const float* W1     = (const float*)d_in[1];
    const float* gamma1 = (const float*)d_in[2];
    const float* beta1  = (const float*)d_in[3];
    const float* W2     = (const float*)d_in[4];
    const float* gamma2 = (const float*)d_in[5];
    const float* beta2  = (const float*)d_in[6];
    const int* in_maps  = (const int*)d_in[7];
    const int* out_maps = (const int*)d_in[8];
    float* out = (float*)d_out;

    char* ws = (char*)d_ws;
    size_t off = 0;
    auto alloc = [&](size_t bytes) -> void* {
        void* p = ws + off;
        off = (off + bytes + 255) & ~(size_t)255;
        return p;
    };
    int* nbrT           = (int*)alloc((size_t)27 * NP * 4);                    // 21.6 MB
    __hip_bfloat16* xb  = (__hip_bfloat16*)alloc((size_t)(N_VOX + 1) * 64 * 2); // 25.6 MB (reused as h1b)
    __hip_bfloat16* W1T = (__hip_bfloat16*)alloc((size_t)27 * 4096 * 2);
    __hip_bfloat16* W2T = (__hip_bfloat16*)alloc((size_t)27 * 4096 * 2);
    __hip_bfloat16* h   = (__hip_bfloat16*)alloc((size_t)N_VOX * 64 * 2);      // 25.6 MB
    float* sums         = (float*)alloc(256 * 4);
    __hip_bfloat16* h1b = xb;   // xb dead after conv1; reuse for BN1(relu) output

    const long elem_x = (long)(N_VOX + 1) * 64;

    fill_kernel   <<<dim3((NP / 4 + 255) / 256, 27), 256, 0, stream>>>(nbrT, sums);
    scatter_kernel<<<26 * P_PAIR / 256, 256, 0, stream>>>(out_maps, in_maps, nbrT);
    cast_x_kernel <<<(int)((elem_x / 4 + 255) / 256), 256, 0, stream>>>(x, xb);
    cast_w_kernel <<<(27 * 4096 + 255) / 256, 256, 0, stream>>>(W1, W2, W1T, W2T);

    conv_kernel   <<<NP / 128, 256, 0, stream>>>(xb, W1T, nbrT, h, sums);
    bnrelu_kernel <<<(int)((elem_x / 4 + 255) / 256), 256, 0, stream>>>(h, sums, gamma1, beta1, h1b);

    conv_kernel   <<<NP / 128, 256, 0, stream>>>(h1b, W2T, nbrT, h, sums + 128);
    final_kernel  <<<(int)(((long)N_VOX * 64 / 4 + 255) / 256), 256, 0, stream>>>(h, x, sums + 128, gamma2, beta2, out);
}